// Round 1
// baseline (47866.025 us; speedup 1.0000x reference)
//
#include <hip/hip_runtime.h>
#include <hip/hip_fp16.h>
#include <hip/hip_cooperative_groups.h>

namespace cg = cooperative_groups;

#define B_ 256
#define T_ 512
#define D_ 128
#define H_ 2048
#define C_ 128

typedef _Float16 half8 __attribute__((ext_vector_type(8)));
typedef float floatx4 __attribute__((ext_vector_type(4)));

// ---- W_hh fp32 [K=H][N=H] row-major  ->  BT fp16 [N][K] (transposed) ----
__global__ void convert_whh(const float* __restrict__ W, _Float16* __restrict__ BT) {
    __shared__ float tile[64][65];                 // +1 pad: conflict-free transpose
    const int kb = blockIdx.x * 64, nb = blockIdx.y * 64;
    const int c = threadIdx.x & 63, r0 = threadIdx.x >> 6;
#pragma unroll
    for (int i = 0; i < 16; ++i) {
        int r = (i << 2) + r0;
        tile[r][c] = W[(size_t)(kb + r) * H_ + nb + c];   // coalesced read
    }
    __syncthreads();
#pragma unroll
    for (int i = 0; i < 16; ++i) {
        int n = (i << 2) + r0;
        BT[(size_t)(nb + n) * H_ + kb + c] = (_Float16)tile[c][n];  // coalesced write
    }
}

// ---- h0 = tanh(W_hx[x[:,0]] + b_h), stored fp16 ----
__global__ void init_h(const int* __restrict__ x, const float* __restrict__ W_hx,
                       const float* __restrict__ b_h, _Float16* __restrict__ h0) {
    int idx = blockIdx.x * blockDim.x + threadIdx.x;   // over B_*H_
    int b = idx >> 11, j = idx & (H_ - 1);
    int xv = x[b * T_];                                // t = 0
    h0[idx] = (_Float16)tanhf(W_hx[xv * H_ + j] + b_h[j]);
}

// ---- the sequential recurrence: one cooperative kernel, grid.sync per step ----
// grid = 512 WGs x 256 thr.  WG tile = 32(M) x 32(N); 4 waves, each one 16x16 C-frag.
// bid mapping: XCD k owns bn in [8k, 8k+8) for all bm  ->  per-XCD B-slice = 1MB (L2-resident).
__global__ __launch_bounds__(256, 2)
void rnn_steps(const _Float16* __restrict__ BT, _Float16* __restrict__ h0,
               _Float16* __restrict__ h1, const int* __restrict__ x,
               const float* __restrict__ W_hx, const float* __restrict__ b_h) {
    cg::grid_group grid = cg::this_grid();
    const int bid = blockIdx.x;
    const int xcd = bid & 7;
    const int g   = bid >> 3;
    const int bn  = (xcd << 3) + (g & 7);   // 0..63
    const int bm  = g >> 3;                 // 0..7
    const int tid = threadIdx.x;
    const int l   = tid & 63;
    const int w   = tid >> 6;
    const int wm  = w >> 1, wn = w & 1;
    const int l15 = l & 15;
    const int kl  = (l >> 4) << 3;          // lane's k-offset within a K=32 step

    const int arow  = (bm << 5) + (wm << 4) + l15;               // batch row of A frag
    const int bcol  = (bn << 5) + (wn << 4) + l15;               // N col of B frag (== C col)
    const int crow0 = (bm << 5) + (wm << 4) + ((l >> 4) << 2);   // C frag row base
    const float bh_c = b_h[bcol];

    for (int t = 1; t < T_; ++t) {
        const _Float16* __restrict__ hc = (t & 1) ? h0 : h1;  // h after step t-1
        _Float16* __restrict__ hn       = (t & 1) ? h1 : h0;  // h after step t
        const half8* ap = (const half8*)(hc + (size_t)arow * H_ + kl);
        const half8* bp = (const half8*)(BT + (size_t)bcol * H_ + kl);
        floatx4 acc = {0.f, 0.f, 0.f, 0.f};
#pragma unroll 8
        for (int k = 0; k < H_ / 32; ++k) {
            half8 a = ap[k * 4];            // 16B contiguous per lane
            half8 b = bp[k * 4];
            acc = __builtin_amdgcn_mfma_f32_16x16x32_f16(a, b, acc, 0, 0, 0);
        }
        // epilogue: z = h@W_hh + W_hx[x[b,t]] + b_h ; h_new = tanh(z)
#pragma unroll
        for (int j = 0; j < 4; ++j) {
            int r  = crow0 + j;
            int xv = x[r * T_ + t];
            float z = acc[j] + W_hx[xv * H_ + bcol] + bh_c;
            hn[(size_t)r * H_ + bcol] = (_Float16)tanhf(z);
        }
        grid.sync();   // includes device-scope fence (release-acquire)
    }
}

// ---- out[b,c] = sum_j h[b,j] * W_ph[j,c] + b_p[c]  (fp32) ----
__global__ void final_proj(const _Float16* __restrict__ h, const float* __restrict__ W_ph,
                           const float* __restrict__ b_p, float* __restrict__ out) {
    __shared__ float part[C_];
    const int b = blockIdx.x;
    const int c = threadIdx.x & (C_ - 1);
    const int hh = threadIdx.x >> 7;       // K-half
    const int j0 = hh * (H_ / 2);
    float acc = 0.f;
#pragma unroll 4
    for (int j = j0; j < j0 + H_ / 2; ++j)
        acc = fmaf((float)h[(size_t)b * H_ + j], W_ph[j * C_ + c], acc);
    if (hh) part[c] = acc;
    __syncthreads();
    if (!hh) out[b * C_ + c] = acc + part[c] + b_p[c];
}

extern "C" void kernel_launch(void* const* d_in, const int* in_sizes, int n_in,
                              void* d_out, int out_size, void* d_ws, size_t ws_size,
                              hipStream_t stream) {
    const int*   x    = (const int*)d_in[0];
    const float* W_hx = (const float*)d_in[1];
    const float* W_hh = (const float*)d_in[2];
    const float* W_ph = (const float*)d_in[3];
    const float* b_h  = (const float*)d_in[4];
    const float* b_p  = (const float*)d_in[5];
    float* out = (float*)d_out;

    char* ws = (char*)d_ws;
    _Float16* BT = (_Float16*)ws;                                    // 8 MB
    _Float16* h0 = (_Float16*)(ws + (size_t)H_ * H_ * 2);            // 1 MB
    _Float16* h1 = (_Float16*)(ws + (size_t)H_ * H_ * 2 + (size_t)B_ * H_ * 2);  // 1 MB

    convert_whh<<<dim3(H_ / 64, H_ / 64), 256, 0, stream>>>(W_hh, BT);
    init_h<<<(B_ * H_) / 256, 256, 0, stream>>>(x, W_hx, b_h, h0);

    void* args[] = {(void*)&BT, (void*)&h0, (void*)&h1,
                    (void*)&x, (void*)&W_hx, (void*)&b_h};
    hipLaunchCooperativeKernel((void*)rnn_steps, dim3(512), dim3(256), args, 0, stream);

    // h after t=511 lives in h1 (511 & 1 == 1)
    final_proj<<<B_, 256, 0, stream>>>(h1, W_ph, b_p, out);
}

// Round 3
// 18761.699 us; speedup vs baseline: 2.5513x; 2.5513x over previous
//
#include <hip/hip_runtime.h>
#include <hip/hip_fp16.h>

#define B_ 256
#define T_ 512
#define D_ 128
#define H_ 2048
#define C_ 128
#define BSTRIDE 2056   // 2048 + 8 fp16 (+16B) pad: row byte-stride 4112 -> 2-way max bank aliasing (free)

typedef _Float16 half8 __attribute__((ext_vector_type(8)));
typedef float floatx4 __attribute__((ext_vector_type(4)));

// ---- h0 = tanh(W_hx[x[:,0]] + b_h) fp16; also zero the 512 barrier counters ----
__global__ void init_h(const int* __restrict__ x, const float* __restrict__ W_hx,
                       const float* __restrict__ b_h, _Float16* __restrict__ h0,
                       unsigned* __restrict__ cnt) {
    int idx = blockIdx.x * blockDim.x + threadIdx.x;   // over B_*H_
    if (idx < 512) cnt[idx] = 0;                       // blocks 0..1 cover all counters
    int b = idx >> 11, j = idx & (H_ - 1);
    int xv = x[b * T_];                                // t = 0
    h0[idx] = (_Float16)tanhf(W_hx[(size_t)xv * H_ + j] + b_h[j]);
}

// ---- recurrence: 256 WGs (1/CU) x 256 thr; WG tile 64(M) x 32(N); W_hh^T slice lives in LDS ----
// bid -> group = bid&7 (XCD round-robin heuristic): group k owns col-blocks [8k,8k+8)
// => h is pulled into each XCD's L2 once per step; W_hh never re-read after prologue.
__global__ __launch_bounds__(256, 1)
void rnn_steps(const float* __restrict__ W_hh, _Float16* __restrict__ h0,
               _Float16* __restrict__ h1, const int* __restrict__ x,
               const float* __restrict__ W_hx, const float* __restrict__ b_h,
               unsigned* __restrict__ cnt) {
    extern __shared__ _Float16 bs[];   // [32 cols][BSTRIDE k]
    const int bid = blockIdx.x;
    const int grp = bid & 7;
    const int g   = bid >> 3;
    const int colblock = grp * 8 + (g & 7);  // 0..63
    const int rowblock = g >> 3;             // 0..3
    const int nb  = colblock * 32;
    const int tid = threadIdx.x;

    // one-time: load + convert + transpose W_hh slice (32 cols, all K) into LDS
    {
        const int c  = (tid & 7) * 4;
        const int kr = tid >> 3;             // 0..31
        for (int k = kr; k < H_; k += 32) {
            const float4 wv = *(const float4*)(W_hh + (size_t)k * H_ + nb + c);
            bs[(c + 0) * BSTRIDE + k] = (_Float16)wv.x;
            bs[(c + 1) * BSTRIDE + k] = (_Float16)wv.y;
            bs[(c + 2) * BSTRIDE + k] = (_Float16)wv.z;
            bs[(c + 3) * BSTRIDE + k] = (_Float16)wv.w;
        }
    }
    __syncthreads();

    const int w    = tid >> 6;               // wave 0..3 -> rows w*16..w*16+15
    const int l    = tid & 63;
    const int l15  = l & 15;
    const int kl   = (l >> 4) << 3;          // lane k-offset within K=32 step
    const int rbase = rowblock * 64 + w * 16;
    const int arow  = rbase + l15;
    const _Float16* bp0 = bs + l15 * BSTRIDE + kl;          // cols nb+0..15
    const _Float16* bp1 = bs + (16 + l15) * BSTRIDE + kl;   // cols nb+16..31
    const int c0 = nb + l15;
    const float bh0 = b_h[c0], bh1 = b_h[c0 + 16];

    unsigned* gcnt  = cnt;                   // global: +1 per group per step
    unsigned* mycnt = cnt + 64 + 32 * grp;   // per-group counters, 128B apart

    for (int t = 1; t < T_; ++t) {
        const _Float16* __restrict__ hc = (t & 1) ? h0 : h1;  // h after step t-1
        _Float16* __restrict__ hn       = (t & 1) ? h1 : h0;
        const _Float16* ap = hc + (size_t)arow * H_ + kl;
        floatx4 acc0 = {0.f, 0.f, 0.f, 0.f}, acc1 = {0.f, 0.f, 0.f, 0.f};
#pragma unroll 8
        for (int k0 = 0; k0 < H_ / 32; ++k0) {
            half8 a  = *(const half8*)(ap  + k0 * 32);   // 16B global (L2-resident h)
            half8 b0 = *(const half8*)(bp0 + k0 * 32);   // ds_read_b128
            half8 b1 = *(const half8*)(bp1 + k0 * 32);
            acc0 = __builtin_amdgcn_mfma_f32_16x16x32_f16(a, b0, acc0, 0, 0, 0);
            acc1 = __builtin_amdgcn_mfma_f32_16x16x32_f16(a, b1, acc1, 0, 0, 0);
        }
#pragma unroll
        for (int jj = 0; jj < 4; ++jj) {
            int r  = rbase + ((l >> 4) << 2) + jj;
            int xv = x[r * T_ + t];
            float z0 = acc0[jj] + W_hx[(size_t)xv * H_ + c0]      + bh0;
            float z1 = acc1[jj] + W_hx[(size_t)xv * H_ + c0 + 16] + bh1;
            hn[(size_t)r * H_ + c0]      = (_Float16)tanhf(z0);
            hn[(size_t)r * H_ + c0 + 16] = (_Float16)tanhf(z1);
        }
        // ---- lightweight monotonic grid barrier (two-level, overlap-safe) ----
        __syncthreads();   // all waves' h-stores issued & complete to L2 (vmcnt drain)
        if (tid == 0) {
            // release: publish this WG's stores (wbL2) with the group arrive
            unsigned prev = __hip_atomic_fetch_add(mycnt, 1u, __ATOMIC_ACQ_REL,
                                                   __HIP_MEMORY_SCOPE_AGENT);
            if (prev == (unsigned)(32 * t - 1))   // last of this group's 32 WGs for step t
                __hip_atomic_fetch_add(gcnt, 1u, __ATOMIC_RELEASE,
                                       __HIP_MEMORY_SCOPE_AGENT);
            // acquire: spin until all 8 groups published step t
            while (__hip_atomic_load(gcnt, __ATOMIC_ACQUIRE,
                                     __HIP_MEMORY_SCOPE_AGENT) < (unsigned)(8 * t))
                __builtin_amdgcn_s_sleep(1);
        }
        __syncthreads();   // rest of WG waits for tid0's acquire (L1/L2 inv done on this CU)
    }
}

// ---- out[b,c] = h[b,:] @ W_ph + b_p (fp32) ----
__global__ void final_proj(const _Float16* __restrict__ h, const float* __restrict__ W_ph,
                           const float* __restrict__ b_p, float* __restrict__ out) {
    __shared__ float part[C_];
    const int b  = blockIdx.x;
    const int c  = threadIdx.x & (C_ - 1);
    const int hh = threadIdx.x >> 7;
    const int j0 = hh * (H_ / 2);
    float acc = 0.f;
#pragma unroll 4
    for (int j = j0; j < j0 + H_ / 2; ++j)
        acc = fmaf((float)h[(size_t)b * H_ + j], W_ph[j * C_ + c], acc);
    if (hh) part[c] = acc;
    __syncthreads();
    if (!hh) out[b * C_ + c] = acc + part[c] + b_p[c];
}

extern "C" void kernel_launch(void* const* d_in, const int* in_sizes, int n_in,
                              void* d_out, int out_size, void* d_ws, size_t ws_size,
                              hipStream_t stream) {
    const int*   x    = (const int*)d_in[0];
    const float* W_hx = (const float*)d_in[1];
    const float* W_hh = (const float*)d_in[2];
    const float* W_ph = (const float*)d_in[3];
    const float* b_h  = (const float*)d_in[4];
    const float* b_p  = (const float*)d_in[5];
    float* out = (float*)d_out;

    char* ws = (char*)d_ws;
    _Float16* h0  = (_Float16*)ws;                                   // 1 MB
    _Float16* h1  = (_Float16*)(ws + (size_t)B_ * H_ * 2);           // 1 MB
    unsigned* cnt = (unsigned*)(ws + (size_t)2 * B_ * H_ * 2);       // 2 KB (512 u32)

    init_h<<<(B_ * H_) / 256, 256, 0, stream>>>(x, W_hx, b_h, h0, cnt);

    const int smem = 32 * BSTRIDE * 2;   // 131584 B
    hipFuncSetAttribute((const void*)rnn_steps,
                        hipFuncAttributeMaxDynamicSharedMemorySize, smem);

    const float* whh = W_hh; _Float16* ph0 = h0; _Float16* ph1 = h1;
    const int* px = x; const float* pwhx = W_hx; const float* pbh = b_h;
    unsigned* pcnt = cnt;
    void* args[] = {(void*)&whh, (void*)&ph0, (void*)&ph1,
                    (void*)&px, (void*)&pwhx, (void*)&pbh, (void*)&pcnt};
    hipError_t e = hipLaunchCooperativeKernel((void*)rnn_steps, dim3(256), dim3(256),
                                              args, smem, stream);
    if (e != hipSuccess) {
        // fallback: plain launch — 1 WG/CU x 256 WGs co-schedules on 256 CUs
        rnn_steps<<<dim3(256), dim3(256), smem, stream>>>(whh, ph0, ph1, px, pwhx, pbh, pcnt);
    }

    // h after t=511 lives in h1
    final_proj<<<B_, 256, 0, stream>>>(h1, W_ph, b_p, out);
}

// Round 4
// 11417.258 us; speedup vs baseline: 4.1924x; 1.6433x over previous
//
#include <hip/hip_runtime.h>
#include <hip/hip_fp16.h>

#define B_ 256
#define T_ 512
#define D_ 128
#define H_ 2048
#define C_ 128
#define BSTRIDE 2056   // 2048 + 8 fp16 (+16B) pad: byte stride 4112 -> 2-way max bank aliasing (floor)

typedef _Float16 half8 __attribute__((ext_vector_type(8)));
typedef float floatx4 __attribute__((ext_vector_type(4)));

// ---- h0 = tanh(W_hx[x[:,0]] + b_h) fp16; zero the 512 barrier counter slots ----
__global__ void init_h(const int* __restrict__ x, const float* __restrict__ W_hx,
                       const float* __restrict__ b_h, _Float16* __restrict__ h0,
                       unsigned* __restrict__ cnt) {
    int idx = blockIdx.x * blockDim.x + threadIdx.x;   // over B_*H_
    if (idx < 512) cnt[idx] = 0;
    int b = idx >> 11, j = idx & (H_ - 1);
    int xv = x[b * T_];                                // t = 0
    h0[idx] = (_Float16)tanhf(W_hx[(size_t)xv * H_ + j] + b_h[j]);
}

// ---- recurrence: 256 WGs (1/CU) x 256 thr; WG tile 64(M) x 32(N); W_hh^T slice in LDS ----
// rowblock = bid>>6 owns batch rows [64*rb, 64*rb+64); its h-slice is produced & consumed
// ONLY by the 64 WGs sharing rb  => per-rowblock barrier (64 arrivals), 4 independent groups.
// bid&7 round-robins XCDs: each XCD gets 8 WGs of each rowblock => h pulled into each L2 once/step.
__global__ __launch_bounds__(256, 1)
void rnn_steps(const float* __restrict__ W_hh, _Float16* __restrict__ h0,
               _Float16* __restrict__ h1, const int* __restrict__ x,
               const float* __restrict__ W_hx, const float* __restrict__ b_h,
               unsigned* __restrict__ cnt) {
    extern __shared__ _Float16 bs[];   // [32 cols][BSTRIDE k]
    const int bid = blockIdx.x;
    const int grp = bid & 7;
    const int g   = bid >> 3;
    const int colblock = grp * 8 + (g & 7);  // 0..63
    const int rowblock = g >> 3;             // 0..3  (== bid>>6)
    const int nb  = colblock * 32;
    const int tid = threadIdx.x;

    // one-time: load + convert + transpose W_hh slice (32 cols, all K) into LDS
    {
        const int c  = (tid & 7) * 4;
        const int kr = tid >> 3;             // 0..31
        for (int k = kr; k < H_; k += 32) {
            const float4 wv = *(const float4*)(W_hh + (size_t)k * H_ + nb + c);
            bs[(c + 0) * BSTRIDE + k] = (_Float16)wv.x;
            bs[(c + 1) * BSTRIDE + k] = (_Float16)wv.y;
            bs[(c + 2) * BSTRIDE + k] = (_Float16)wv.z;
            bs[(c + 3) * BSTRIDE + k] = (_Float16)wv.w;
        }
    }
    __syncthreads();

    const int w    = tid >> 6;               // wave 0..3 -> rows w*16..w*16+15
    const int l    = tid & 63;
    const int l15  = l & 15;
    const int kl   = (l >> 4) << 3;          // lane k-offset within K=32 step
    const int rbase = rowblock * 64 + w * 16;
    const int arow  = rbase + l15;
    const int r0    = rbase + ((l >> 4) << 2);   // C-frag row base for this lane
    const _Float16* bp0 = bs + l15 * BSTRIDE + kl;          // cols nb+0..15
    const _Float16* bp1 = bs + (16 + l15) * BSTRIDE + kl;   // cols nb+16..31
    const int c0 = nb + l15;
    const float bh0 = b_h[c0], bh1 = b_h[c0 + 16];

    unsigned* mycnt = cnt + rowblock * 64;   // one counter per rowblock, 256B apart

    for (int t = 1; t < T_; ++t) {
        const _Float16* __restrict__ hc = (t & 1) ? h0 : h1;  // h after step t-1
        _Float16* __restrict__ hn       = (t & 1) ? h1 : h0;

        // prefetch epilogue gathers: x[r,t] then W_hx[xv] — latency hides under the K-loop
        int   xv[4];
        float wx0[4], wx1[4];
#pragma unroll
        for (int jj = 0; jj < 4; ++jj) xv[jj] = x[(r0 + jj) * T_ + t];
#pragma unroll
        for (int jj = 0; jj < 4; ++jj) {
            wx0[jj] = W_hx[(size_t)xv[jj] * H_ + c0];
            wx1[jj] = W_hx[(size_t)xv[jj] * H_ + c0 + 16];
        }

        const _Float16* ap = hc + (size_t)arow * H_ + kl;
        floatx4 acc0 = {0.f, 0.f, 0.f, 0.f}, acc1 = {0.f, 0.f, 0.f, 0.f};
#pragma unroll 8
        for (int k0 = 0; k0 < H_ / 32; ++k0) {
            half8 a  = *(const half8*)(ap  + k0 * 32);   // 16B global (L2-resident h)
            half8 b0 = *(const half8*)(bp0 + k0 * 32);   // ds_read_b128
            half8 b1 = *(const half8*)(bp1 + k0 * 32);
            acc0 = __builtin_amdgcn_mfma_f32_16x16x32_f16(a, b0, acc0, 0, 0, 0);
            acc1 = __builtin_amdgcn_mfma_f32_16x16x32_f16(a, b1, acc1, 0, 0, 0);
        }
#pragma unroll
        for (int jj = 0; jj < 4; ++jj) {
            float z0 = acc0[jj] + wx0[jj] + bh0;
            float z1 = acc1[jj] + wx1[jj] + bh1;
            hn[(size_t)(r0 + jj) * H_ + c0]      = (_Float16)tanhf(z0);
            hn[(size_t)(r0 + jj) * H_ + c0 + 16] = (_Float16)tanhf(z1);
        }

        // ---- per-rowblock monotonic barrier: relaxed spin, one-shot fences ----
        __syncthreads();                     // all waves' stores issued
        if (tid == 0) {
            __builtin_amdgcn_fence(__ATOMIC_RELEASE, "agent");   // one wbL2: publish h-stores
            __hip_atomic_fetch_add(mycnt, 1u, __ATOMIC_RELAXED, __HIP_MEMORY_SCOPE_AGENT);
            while (__hip_atomic_load(mycnt, __ATOMIC_RELAXED, __HIP_MEMORY_SCOPE_AGENT)
                   < (unsigned)(64 * t))
                __builtin_amdgcn_s_sleep(2); // relaxed poll: NO cache maintenance
            __builtin_amdgcn_fence(__ATOMIC_ACQUIRE, "agent");   // one inv: fresh h next step
        }
        __syncthreads();
    }
}

// ---- out[b,c] = h[b,:] @ W_ph + b_p (fp32) ----
__global__ void final_proj(const _Float16* __restrict__ h, const float* __restrict__ W_ph,
                           const float* __restrict__ b_p, float* __restrict__ out) {
    __shared__ float part[C_];
    const int b  = blockIdx.x;
    const int c  = threadIdx.x & (C_ - 1);
    const int hh = threadIdx.x >> 7;
    const int j0 = hh * (H_ / 2);
    float acc = 0.f;
#pragma unroll 4
    for (int j = j0; j < j0 + H_ / 2; ++j)
        acc = fmaf((float)h[(size_t)b * H_ + j], W_ph[j * C_ + c], acc);
    if (hh) part[c] = acc;
    __syncthreads();
    if (!hh) out[b * C_ + c] = acc + part[c] + b_p[c];
}

extern "C" void kernel_launch(void* const* d_in, const int* in_sizes, int n_in,
                              void* d_out, int out_size, void* d_ws, size_t ws_size,
                              hipStream_t stream) {
    const int*   x    = (const int*)d_in[0];
    const float* W_hx = (const float*)d_in[1];
    const float* W_hh = (const float*)d_in[2];
    const float* W_ph = (const float*)d_in[3];
    const float* b_h  = (const float*)d_in[4];
    const float* b_p  = (const float*)d_in[5];
    float* out = (float*)d_out;

    char* ws = (char*)d_ws;
    _Float16* h0  = (_Float16*)ws;                                   // 1 MB
    _Float16* h1  = (_Float16*)(ws + (size_t)B_ * H_ * 2);           // 1 MB
    unsigned* cnt = (unsigned*)(ws + (size_t)2 * B_ * H_ * 2);       // 2 KB (512 u32)

    init_h<<<(B_ * H_) / 256, 256, 0, stream>>>(x, W_hx, b_h, h0, cnt);

    const int smem = 32 * BSTRIDE * 2;   // 131584 B
    hipFuncSetAttribute((const void*)rnn_steps,
                        hipFuncAttributeMaxDynamicSharedMemorySize, smem);

    const float* whh = W_hh; _Float16* ph0 = h0; _Float16* ph1 = h1;
    const int* px = x; const float* pwhx = W_hx; const float* pbh = b_h;
    unsigned* pcnt = cnt;
    void* args[] = {(void*)&whh, (void*)&ph0, (void*)&ph1,
                    (void*)&px, (void*)&pwhx, (void*)&pbh, (void*)&pcnt};
    hipError_t e = hipLaunchCooperativeKernel((void*)rnn_steps, dim3(256), dim3(256),
                                              args, smem, stream);
    if (e != hipSuccess) {
        // fallback: plain launch — 1 WG/CU x 256 WGs co-schedules on 256 CUs
        rnn_steps<<<dim3(256), dim3(256), smem, stream>>>(whh, ph0, ph1, px, pwhx, pbh, pcnt);
    }

    // h after t=511 lives in h1
    final_proj<<<B_, 256, 0, stream>>>(h1, W_ph, b_p, out);
}